// Round 1
// baseline (127.026 us; speedup 1.0000x reference)
//
#include <hip/hip_runtime.h>

// Problem constants: B=8, M=12, N=32, D=256, C=1024, C/R=512, BM=96.
//
// ws layout (floats):
//   Gp   [4][96][1024]  partial Gram (d-split by 4)   off 0       len 393216
//   Sp   [4][96][32]    partial row sums              off 393216  len 12288
//   Ssum [96][32]       full row sums                 off 405504  len 3072
//   Ht   [96][512]      relu(W1@ef), bm-major         off 408576  len 49152
//   Et   [96][1024]     sigmoid(W2@h), bm-major       off 457728  len 98304
// total 556032 floats = 2.2 MB

__device__ __forceinline__ float dot4(float4 a, float4 b) {
    return a.x*b.x + a.y*b.y + a.z*b.z + a.w*b.w;
}
__device__ __forceinline__ void fma4(float4& acc, float s, float4 v) {
    acc.x += s*v.x; acc.y += s*v.y; acc.z += s*v.z; acc.w += s*v.w;
}

// ---------------- Kernel 1: partial Gram + partial row sums -----------------
// grid 384 = 96 bm x 4 d-slices of 64; block 256.
__global__ __launch_bounds__(256) void kg_kernel(const float* __restrict__ x,
                                                 float* __restrict__ Gp,
                                                 float* __restrict__ Sp) {
    int bm = blockIdx.x >> 2;
    int s  = blockIdx.x & 3;
    int t  = threadIdx.x;
    __shared__ float4 xs4[32][17];   // 32 rows x 16 f4 (64 floats), pad 17
    __shared__ alignas(16) float Gs[1024];

    const float4* x4 = (const float4*)x;
    int n0 = t >> 4, dq = t & 15;    // rows 0..15 (i=0) and 16..31 (i=1)
    int n1 = n0 + 16;
    float4 v0 = x4[bm*2048 + n0*64 + s*16 + dq];
    float4 v1 = x4[bm*2048 + n1*64 + s*16 + dq];
    xs4[n0][dq] = v0;
    xs4[n1][dq] = v1;
    float p0 = v0.x+v0.y+v0.z+v0.w;
    float p1 = v1.x+v1.y+v1.z+v1.w;
    #pragma unroll
    for (int m = 1; m < 16; m <<= 1) {
        p0 += __shfl_xor(p0, m, 16);
        p1 += __shfl_xor(p1, m, 16);
    }
    if (dq == 0) {
        Sp[s*3072 + bm*32 + n0] = p0;
        Sp[s*3072 + bm*32 + n1] = p1;
    }
    __syncthreads();

    // 2x2 register tile: rows (a, a+16) x (b, b+16) -> <=2-way LDS conflicts
    int a = t >> 4, b = t & 15;
    float g00=0.f, g01=0.f, g10=0.f, g11=0.f;
    #pragma unroll
    for (int t4 = 0; t4 < 16; ++t4) {
        float4 a0 = xs4[a][t4];
        float4 a1 = xs4[a+16][t4];
        float4 b0 = xs4[b][t4];
        float4 b1 = xs4[b+16][t4];
        g00 += dot4(a0, b0); g01 += dot4(a0, b1);
        g10 += dot4(a1, b0); g11 += dot4(a1, b1);
    }
    Gs[a*32 + b]           = g00;
    Gs[a*32 + b + 16]      = g01;
    Gs[(a+16)*32 + b]      = g10;
    Gs[(a+16)*32 + b + 16] = g11;
    __syncthreads();
    ((float4*)Gp)[s*24576 + bm*256 + t] = ((const float4*)Gs)[t];
}

// ---------------- Kernel 2: ef synth + GEMM1 + relu -------------------------
// grid (16 o-tiles, 12 bm-tiles); block (32 o-lanes, 8 bm).
__global__ __launch_bounds__(256) void k2_kernel(const float* __restrict__ W1,
                                                 const float* __restrict__ Sp,
                                                 float* __restrict__ Ssum,
                                                 float* __restrict__ Ht) {
    __shared__ float S_lds[8][32];
    __shared__ alignas(16) float ef[8][1024];   // 32 KB
    int tx = threadIdx.x, ty = threadIdx.y;
    int t = ty*32 + tx;
    int bm_t = blockIdx.y, o_t = blockIdx.x;
    {
        int bl = t >> 5, n = t & 31;
        int bm = bm_t*8 + bl;
        float s_ = 0.f;
        #pragma unroll
        for (int s = 0; s < 4; ++s) s_ += Sp[s*3072 + bm*32 + n];
        S_lds[bl][n] = s_;
        if (o_t == 0) Ssum[bm*32 + n] = s_;   // one writer tile per bm
    }
    __syncthreads();
    // ef[c=n*32+k] = (S_n + 2*S_k - (n==k)*S_k) / 512
    #pragma unroll
    for (int i = 0; i < 32; ++i) {
        int idx = t + 256*i;
        int bl = idx >> 10, c = idx & 1023;
        int nn = c >> 5, kk = c & 31;
        float sn = S_lds[bl][nn], sk = S_lds[bl][kk];
        ef[bl][c] = (sn + 2.f*sk - (nn == kk ? sk : 0.f)) * (1.f/512.f);
    }
    __syncthreads();
    int o = o_t*32 + tx;
    const float4* w  = (const float4*)(W1 + o*1024);
    const float4* e4 = (const float4*)(&ef[ty][0]);   // broadcast across lanes
    float acc = 0.f;
    #pragma unroll 8
    for (int c4 = 0; c4 < 256; ++c4) acc += dot4(w[c4], e4[c4]);
    int bm = bm_t*8 + ty;
    Ht[bm*512 + o] = fmaxf(acc, 0.f);
}

// ---------------- Kernel 3: GEMM2 + sigmoid ---------------------------------
// grid (32 c-tiles, 12 bm-tiles); block (32 c-lanes, 8 bm).
__global__ __launch_bounds__(256) void k3_kernel(const float* __restrict__ W2,
                                                 const float* __restrict__ Ht,
                                                 float* __restrict__ Et) {
    __shared__ float4 hl4[8][128];   // 16 KB
    int tx = threadIdx.x, ty = threadIdx.y;
    int t = ty*32 + tx;
    int c_t = blockIdx.x, bm_t = blockIdx.y;
    const float4* Ht4 = (const float4*)Ht;
    #pragma unroll
    for (int i = 0; i < 4; ++i) {
        int idx = t + 256*i;                 // 0..1023
        int bl = idx >> 7, o4 = idx & 127;
        hl4[bl][o4] = Ht4[(bm_t*8 + bl)*128 + o4];
    }
    __syncthreads();
    int c = c_t*32 + tx;
    const float4* w = (const float4*)(W2 + c*512);
    float acc = 0.f;
    #pragma unroll 8
    for (int o4 = 0; o4 < 128; ++o4) acc += dot4(w[o4], hl4[ty][o4]);
    float e = 1.f / (1.f + __expf(-acc));
    Et[(bm_t*8 + ty)*1024 + c] = e;
}

// ---------------- Kernel 4: cov sign + softmax + att@x ----------------------
// grid 192 = 96 bm x 2 d-halves of 128; block 256.
__global__ __launch_bounds__(256) void k4_kernel(const float* __restrict__ x,
                                                 const float* __restrict__ Gp,
                                                 const float* __restrict__ Ssum,
                                                 const float* __restrict__ Et,
                                                 float* __restrict__ out) {
    int bm = blockIdx.x >> 1;
    int h  = blockIdx.x & 1;
    int t  = threadIdx.x;
    __shared__ alignas(16) float att[32][36];   // row stride 9 f4
    __shared__ float4 xs4[32][33];              // half of x tile, pad 33

    // phase A: per-row masked softmax (8 lanes per row, 4 k each)
    {
        int r = t >> 3, q = t & 7;
        const float4* Gp4 = (const float4*)Gp;
        float4 g = Gp4[bm*256 + r*8 + q];
        #pragma unroll
        for (int s = 1; s < 4; ++s) {
            float4 gg = Gp4[s*24576 + bm*256 + r*8 + q];
            g.x += gg.x; g.y += gg.y; g.z += gg.z; g.w += gg.w;
        }
        float  sr = Ssum[bm*32 + r] * (1.f/256.f);
        float4 sk = ((const float4*)Ssum)[bm*8 + q];
        float4 e  = ((const float4*)Et)[bm*256 + r*8 + q];
        float4 lg;
        lg.x = (g.x - sr*sk.x) > 0.f ? e.x : -1e12f;
        lg.y = (g.y - sr*sk.y) > 0.f ? e.y : -1e12f;
        lg.z = (g.z - sr*sk.z) > 0.f ? e.z : -1e12f;
        lg.w = (g.w - sr*sk.w) > 0.f ? e.w : -1e12f;
        float m = fmaxf(fmaxf(lg.x, lg.y), fmaxf(lg.z, lg.w));
        m = fmaxf(m, __shfl_xor(m, 1, 8));
        m = fmaxf(m, __shfl_xor(m, 2, 8));
        m = fmaxf(m, __shfl_xor(m, 4, 8));
        float4 p;
        p.x = __expf(lg.x - m); p.y = __expf(lg.y - m);
        p.z = __expf(lg.z - m); p.w = __expf(lg.w - m);
        float sum = p.x + p.y + p.z + p.w;
        sum += __shfl_xor(sum, 1, 8);
        sum += __shfl_xor(sum, 2, 8);
        sum += __shfl_xor(sum, 4, 8);
        float inv = 1.f / sum;
        p.x *= inv; p.y *= inv; p.z *= inv; p.w *= inv;
        ((float4*)att)[r*9 + q] = p;
    }
    // phase A2: stage this d-half of x
    {
        const float4* x4 = (const float4*)x;
        #pragma unroll
        for (int i = 0; i < 4; ++i) {
            int idx = t + 256*i;
            int n = idx >> 5, dq = idx & 31;
            xs4[n][dq] = x4[bm*2048 + n*64 + h*32 + dq];
        }
    }
    __syncthreads();

    // phase B: out[n, dhalf] = sum_k att[n,k] * x[k, dhalf]; 4-row tiles
    int n4 = t >> 5, dq = t & 31;
    float4 acc0 = {0,0,0,0}, acc1 = {0,0,0,0}, acc2 = {0,0,0,0}, acc3 = {0,0,0,0};
    #pragma unroll
    for (int k4 = 0; k4 < 8; ++k4) {
        float4 xa = xs4[k4*4+0][dq];
        float4 xb = xs4[k4*4+1][dq];
        float4 xc = xs4[k4*4+2][dq];
        float4 xd = xs4[k4*4+3][dq];
        float4 w0 = ((const float4*)att)[(n4*4+0)*9 + k4];
        float4 w1 = ((const float4*)att)[(n4*4+1)*9 + k4];
        float4 w2 = ((const float4*)att)[(n4*4+2)*9 + k4];
        float4 w3 = ((const float4*)att)[(n4*4+3)*9 + k4];
        fma4(acc0, w0.x, xa); fma4(acc0, w0.y, xb); fma4(acc0, w0.z, xc); fma4(acc0, w0.w, xd);
        fma4(acc1, w1.x, xa); fma4(acc1, w1.y, xb); fma4(acc1, w1.z, xc); fma4(acc1, w1.w, xd);
        fma4(acc2, w2.x, xa); fma4(acc2, w2.y, xb); fma4(acc2, w2.z, xc); fma4(acc2, w2.w, xd);
        fma4(acc3, w3.x, xa); fma4(acc3, w3.y, xb); fma4(acc3, w3.z, xc); fma4(acc3, w3.w, xd);
    }
    float4* out4 = (float4*)out;
    out4[bm*2048 + (n4*4+0)*64 + h*32 + dq] = acc0;
    out4[bm*2048 + (n4*4+1)*64 + h*32 + dq] = acc1;
    out4[bm*2048 + (n4*4+2)*64 + h*32 + dq] = acc2;
    out4[bm*2048 + (n4*4+3)*64 + h*32 + dq] = acc3;
}

extern "C" void kernel_launch(void* const* d_in, const int* in_sizes, int n_in,
                              void* d_out, int out_size, void* d_ws, size_t ws_size,
                              hipStream_t stream) {
    const float* x  = (const float*)d_in[0];
    const float* W1 = (const float*)d_in[1];
    const float* W2 = (const float*)d_in[2];
    float* out = (float*)d_out;
    float* ws  = (float*)d_ws;

    float* Gp   = ws;             // 393216 floats
    float* Sp   = ws + 393216;    // 12288
    float* Ssum = ws + 405504;    // 3072
    float* Ht   = ws + 408576;    // 49152
    float* Et   = ws + 457728;    // 98304

    kg_kernel<<<384, 256, 0, stream>>>(x, Gp, Sp);
    k2_kernel<<<dim3(16, 12), dim3(32, 8), 0, stream>>>(W1, Sp, Ssum, Ht);
    k3_kernel<<<dim3(32, 12), dim3(32, 8), 0, stream>>>(W2, Ht, Et);
    k4_kernel<<<192, 256, 0, stream>>>(x, Gp, Ssum, Et, out);
}

// Round 2
// 117.450 us; speedup vs baseline: 1.0815x; 1.0815x over previous
//
#include <hip/hip_runtime.h>

// B=8, M=12, N=32, D=256, C=1024, O=C/2=512, BM=96.
//
// ws layout (floats):
//   W1t  [1024][512]  transposed W1        off 0        len 524288
//   W2t  [512][1024]  transposed W2        off 524288   len 524288
//   Ssum [96][32]     row sums of x        off 1048576  len 3072
//   Ht   [96][512]    relu(W1@ef)          off 1051648  len 49152
//   Et   [96][1024]   sigmoid(W2@h)        off 1100800  len 98304
// total 1199104 floats = 4.8 MB

__device__ __forceinline__ float dot4(float4 a, float4 b) {
    return a.x*b.x + a.y*b.y + a.z*b.z + a.w*b.w;
}
__device__ __forceinline__ void fma4(float4& acc, float s, float4 v) {
    acc.x += s*v.x; acc.y += s*v.y; acc.z += s*v.z; acc.w += s*v.w;
}

// ---------------- Kernel A: transpose W1,W2 + row sums ----------------------
// blocks 0..511: W1 tiles; 512..1023: W2 tiles; 1024..1119: Ssum per bm.
__global__ __launch_bounds__(256) void kprep(const float* __restrict__ x,
                                             const float* __restrict__ W1,
                                             const float* __restrict__ W2,
                                             float* __restrict__ W1t,
                                             float* __restrict__ W2t,
                                             float* __restrict__ Ssum) {
    int bid = blockIdx.x;
    if (bid < 1024) {
        __shared__ float tile[32][33];
        int tx = threadIdx.x & 31, ty = threadIdx.x >> 5;   // 32 x 8
        const float* src; float* dst; int r0, c0, sw, dw;
        if (bid < 512) {            // W1[512][1024] -> W1t[1024][512]
            r0 = (bid >> 5) * 32; c0 = (bid & 31) * 32;
            src = W1; dst = W1t; sw = 1024; dw = 512;
        } else {                    // W2[1024][512] -> W2t[512][1024]
            int b = bid - 512;
            r0 = (b >> 4) * 32; c0 = (b & 15) * 32;
            src = W2; dst = W2t; sw = 512; dw = 1024;
        }
        #pragma unroll
        for (int k = 0; k < 4; ++k)
            tile[ty + 8*k][tx] = src[(r0 + ty + 8*k) * sw + c0 + tx];
        __syncthreads();
        #pragma unroll
        for (int k = 0; k < 4; ++k)
            dst[(c0 + ty + 8*k) * dw + r0 + tx] = tile[tx][ty + 8*k];
    } else {
        int bm = bid - 1024;
        const float4* x4 = (const float4*)x;
        int n = threadIdx.x >> 3, dq = threadIdx.x & 7;   // 32 rows x 8 lanes
        float s = 0.f;
        #pragma unroll
        for (int j = 0; j < 8; ++j) {
            float4 v = x4[bm*2048 + n*64 + dq + 8*j];
            s += v.x + v.y + v.z + v.w;
        }
        s += __shfl_xor(s, 1, 8);
        s += __shfl_xor(s, 2, 8);
        s += __shfl_xor(s, 4, 8);
        if (dq == 0) Ssum[bm*32 + n] = s;
    }
}

// ---------------- Kernel B: ef synth + GEMM1 + relu -------------------------
// grid (16 o-tiles, 12 bm-groups); block (32 o-lanes, 8 bm).
// W1t read coalesced (lanes along o); ef broadcast from LDS (pad +4 -> no conflict).
__global__ __launch_bounds__(256) void k2(const float* __restrict__ W1t,
                                          const float* __restrict__ Ssum,
                                          float* __restrict__ Ht) {
    __shared__ float S_l[8][32];
    __shared__ float ef[8][1028];   // pad 4: ty-stride 1028 ≡ 4 banks, 16B aligned
    int tx = threadIdx.x, ty = threadIdx.y;
    int t = ty*32 + tx;
    int oT = blockIdx.x, bmG = blockIdx.y;
    {
        int bl = t >> 5, n = t & 31;
        S_l[bl][n] = Ssum[(bmG*8 + bl)*32 + n];
    }
    __syncthreads();
    // ef[c=n*32+k] = (S_n + 2*S_k - (n==k)*S_k) / 512
    #pragma unroll
    for (int i = 0; i < 32; ++i) {
        int idx = t + 256*i;
        int bl = idx >> 10, c = idx & 1023;
        int nn = c >> 5, kk = c & 31;
        float sn = S_l[bl][nn], sk = S_l[bl][kk];
        ef[bl][c] = (sn + 2.f*sk - (nn == kk ? sk : 0.f)) * (1.f/512.f);
    }
    __syncthreads();
    int o = oT*32 + tx;
    const float* wp = W1t + o;   // column of W1t, row-stride 512
    float acc = 0.f;
    #pragma unroll 4
    for (int c4 = 0; c4 < 256; ++c4) {
        float4 e4 = *((const float4*)&ef[ty][c4*4]);
        float w0 = wp[(4*c4+0)*512];
        float w1 = wp[(4*c4+1)*512];
        float w2 = wp[(4*c4+2)*512];
        float w3 = wp[(4*c4+3)*512];
        acc += w0*e4.x + w1*e4.y + w2*e4.z + w3*e4.w;
    }
    Ht[(bmG*8 + ty)*512 + o] = fmaxf(acc, 0.f);
}

// ---------------- Kernel C: GEMM2 + sigmoid ---------------------------------
// grid (32 c-tiles, 12 bm-groups); block (32 c-lanes, 8 bm).
__global__ __launch_bounds__(256) void k3(const float* __restrict__ W2t,
                                          const float* __restrict__ Ht,
                                          float* __restrict__ Et) {
    __shared__ float hl[8][516];    // pad 4, 16B aligned rows
    int tx = threadIdx.x, ty = threadIdx.y;
    int t = ty*32 + tx;
    int cT = blockIdx.x, bmG = blockIdx.y;
    const float4* Ht4 = (const float4*)Ht;
    #pragma unroll
    for (int i = 0; i < 4; ++i) {
        int idx = t + 256*i;              // 0..1023 = 8 bm x 128 f4
        int bl = idx >> 7, o4 = idx & 127;
        *((float4*)&hl[bl][o4*4]) = Ht4[(bmG*8 + bl)*128 + o4];
    }
    __syncthreads();
    int c = cT*32 + tx;
    const float* wp = W2t + c;   // column of W2t, row-stride 1024
    float acc = 0.f;
    #pragma unroll 4
    for (int o4 = 0; o4 < 128; ++o4) {
        float4 h4 = *((const float4*)&hl[ty][o4*4]);
        acc += wp[(4*o4+0)*1024]*h4.x + wp[(4*o4+1)*1024]*h4.y
             + wp[(4*o4+2)*1024]*h4.z + wp[(4*o4+3)*1024]*h4.w;
    }
    float e = 1.f / (1.f + __expf(-acc));
    Et[(bmG*8 + ty)*1024 + c] = e;
}

// ---------------- Kernel D: Gram + mask + softmax + att@x -------------------
// grid 96 (one block per bm); block 256.
__global__ __launch_bounds__(256) void k4(const float* __restrict__ x,
                                          const float* __restrict__ Ssum,
                                          const float* __restrict__ Et,
                                          float* __restrict__ out) {
    int bm = blockIdx.x;
    int t = threadIdx.x;
    __shared__ float4 xs4[32][65];      // 32 rows x 64 f4 (D=256), pad 65
    __shared__ float att_l[32][36];     // row stride 36 floats (9 f4, aligned)
    __shared__ float S_l[32];

    const float4* x4 = (const float4*)x;
    #pragma unroll
    for (int i = 0; i < 8; ++i) {
        int idx = t + 256*i;            // 0..2047
        xs4[idx >> 6][idx & 63] = x4[bm*2048 + idx];
    }
    if (t < 32) S_l[t] = Ssum[bm*32 + t];
    __syncthreads();

    // Gram 2x2 register tile: rows (a, a+16) x (b, b+16); logits into att_l
    {
        int a = t >> 4, b = t & 15;
        float g00=0.f, g01=0.f, g10=0.f, g11=0.f;
        #pragma unroll 8
        for (int q = 0; q < 64; ++q) {
            float4 a0 = xs4[a][q],    a1 = xs4[a+16][q];
            float4 b0 = xs4[b][q],    b1 = xs4[b+16][q];
            g00 += dot4(a0,b0); g01 += dot4(a0,b1);
            g10 += dot4(a1,b0); g11 += dot4(a1,b1);
        }
        float sa0 = S_l[a]    * (1.f/256.f);
        float sa1 = S_l[a+16] * (1.f/256.f);
        float sb0 = S_l[b], sb1 = S_l[b+16];
        float e00 = Et[bm*1024 + a*32 + b];
        float e01 = Et[bm*1024 + a*32 + b+16];
        float e10 = Et[bm*1024 + (a+16)*32 + b];
        float e11 = Et[bm*1024 + (a+16)*32 + b+16];
        att_l[a][b]       = (g00 - sa0*sb0) > 0.f ? e00 : -1e12f;
        att_l[a][b+16]    = (g01 - sa0*sb1) > 0.f ? e01 : -1e12f;
        att_l[a+16][b]    = (g10 - sa1*sb0) > 0.f ? e10 : -1e12f;
        att_l[a+16][b+16] = (g11 - sa1*sb1) > 0.f ? e11 : -1e12f;
    }
    __syncthreads();

    // masked softmax per row: 8 lanes x 4 cols each
    {
        int r = t >> 3, q = t & 7;
        float4 lg = *((const float4*)&att_l[r][q*4]);
        float m = fmaxf(fmaxf(lg.x,lg.y), fmaxf(lg.z,lg.w));
        m = fmaxf(m, __shfl_xor(m,1,8));
        m = fmaxf(m, __shfl_xor(m,2,8));
        m = fmaxf(m, __shfl_xor(m,4,8));
        float4 p;
        p.x = __expf(lg.x-m); p.y = __expf(lg.y-m);
        p.z = __expf(lg.z-m); p.w = __expf(lg.w-m);
        float s = p.x+p.y+p.z+p.w;
        s += __shfl_xor(s,1,8);
        s += __shfl_xor(s,2,8);
        s += __shfl_xor(s,4,8);
        float inv = 1.f/s;
        p.x*=inv; p.y*=inv; p.z*=inv; p.w*=inv;
        *((float4*)&att_l[r][q*4]) = p;
    }
    __syncthreads();

    // out[r, :] = sum_k att[r,k] * x[k, :]; 4-row register tiles
    int tx = t & 63, wy = t >> 6;
    float4* out4 = (float4*)out;
    #pragma unroll
    for (int g = 0; g < 2; ++g) {
        int r0 = wy*8 + g*4;
        float4 acc0={0,0,0,0}, acc1={0,0,0,0}, acc2={0,0,0,0}, acc3={0,0,0,0};
        #pragma unroll
        for (int kq = 0; kq < 8; ++kq) {
            float4 xa = xs4[kq*4+0][tx];
            float4 xb = xs4[kq*4+1][tx];
            float4 xc = xs4[kq*4+2][tx];
            float4 xd = xs4[kq*4+3][tx];
            float4 w0 = *((const float4*)&att_l[r0+0][kq*4]);
            float4 w1 = *((const float4*)&att_l[r0+1][kq*4]);
            float4 w2 = *((const float4*)&att_l[r0+2][kq*4]);
            float4 w3 = *((const float4*)&att_l[r0+3][kq*4]);
            fma4(acc0,w0.x,xa); fma4(acc0,w0.y,xb); fma4(acc0,w0.z,xc); fma4(acc0,w0.w,xd);
            fma4(acc1,w1.x,xa); fma4(acc1,w1.y,xb); fma4(acc1,w1.z,xc); fma4(acc1,w1.w,xd);
            fma4(acc2,w2.x,xa); fma4(acc2,w2.y,xb); fma4(acc2,w2.z,xc); fma4(acc2,w2.w,xd);
            fma4(acc3,w3.x,xa); fma4(acc3,w3.y,xb); fma4(acc3,w3.z,xc); fma4(acc3,w3.w,xd);
        }
        out4[bm*2048 + (r0+0)*64 + tx] = acc0;
        out4[bm*2048 + (r0+1)*64 + tx] = acc1;
        out4[bm*2048 + (r0+2)*64 + tx] = acc2;
        out4[bm*2048 + (r0+3)*64 + tx] = acc3;
    }
}

extern "C" void kernel_launch(void* const* d_in, const int* in_sizes, int n_in,
                              void* d_out, int out_size, void* d_ws, size_t ws_size,
                              hipStream_t stream) {
    const float* x  = (const float*)d_in[0];
    const float* W1 = (const float*)d_in[1];
    const float* W2 = (const float*)d_in[2];
    float* out = (float*)d_out;
    float* ws  = (float*)d_ws;

    float* W1t  = ws;               // 524288 floats
    float* W2t  = ws + 524288;      // 524288
    float* Ssum = ws + 1048576;     // 3072
    float* Ht   = ws + 1051648;     // 49152
    float* Et   = ws + 1100800;     // 98304

    kprep<<<1120, 256, 0, stream>>>(x, W1, W2, W1t, W2t, Ssum);
    k2<<<dim3(16, 12), dim3(32, 8), 0, stream>>>(W1t, Ssum, Ht);
    k3<<<dim3(32, 12), dim3(32, 8), 0, stream>>>(W2t, Ht, Et);
    k4<<<96, 256, 0, stream>>>(x, Ssum, Et, out);
}

// Round 3
// 81.652 us; speedup vs baseline: 1.5557x; 1.4384x over previous
//
#include <hip/hip_runtime.h>

// B=8, M=12, N=32, D=256, C=1024, O=C/2=512, BM=96.
//
// ws layout (floats):
//   Ssum [96][32]     row sums of x        off 0      len 3072
//   Ht   [96][512]    relu(W1@ef)          off 3072   len 49152
//   Et   [96][1024]   sigmoid(W2@h)        off 52224  len 98304
// total 150528 floats = 0.6 MB. No weight transpose: GEMMs read W row-major
// coalesced (lanes along the contraction dim, shfl-reduce).

__device__ __forceinline__ float dot4(float4 a, float4 b) {
    return a.x*b.x + a.y*b.y + a.z*b.z + a.w*b.w;
}
__device__ __forceinline__ void fma4(float4& acc, float s, float4 v) {
    acc.x += s*v.x; acc.y += s*v.y; acc.z += s*v.z; acc.w += s*v.w;
}

// ---------------- Kernel S: row sums ----------------------------------------
// grid 96; block 256 (32 rows x 8 lanes).
__global__ __launch_bounds__(256) void kS(const float* __restrict__ x,
                                          float* __restrict__ Ssum) {
    int bm = blockIdx.x;
    const float4* x4 = (const float4*)x;
    int n = threadIdx.x >> 3, dq = threadIdx.x & 7;
    float s = 0.f;
    #pragma unroll
    for (int j = 0; j < 8; ++j) {
        float4 v = x4[bm*2048 + n*64 + dq + 8*j];
        s += v.x + v.y + v.z + v.w;
    }
    s += __shfl_xor(s, 1, 8);
    s += __shfl_xor(s, 2, 8);
    s += __shfl_xor(s, 4, 8);
    if (dq == 0) Ssum[bm*32 + n] = s;
}

// ---------------- Kernel B: ef synth + GEMM1 + relu -------------------------
// grid (32 o-tiles of 16, 12 bm-groups of 8); block 256 = 16 clane x 16 og.
// W1[o][c] read row-major coalesced: 16 clanes x float4 = 256 B/row fragment.
// Each thread FMAs its W fragment against 8 bm ef-rows from LDS, then
// shfl-reduces over the 16 clanes.
__global__ __launch_bounds__(256) void k2(const float* __restrict__ W1,
                                          const float* __restrict__ Ssum,
                                          float* __restrict__ Ht) {
    __shared__ float S_l[8][32];
    __shared__ float ef[8][1024];   // 32 KB; b128 reads are <=2-way (free)
    int t = threadIdx.x;
    int clane = t & 15, og = t >> 4;
    int oT = blockIdx.x, bmG = blockIdx.y;
    {
        int bl = t >> 5, n = t & 31;
        S_l[bl][n] = Ssum[(bmG*8 + bl)*32 + n];
    }
    __syncthreads();
    // ef[c=n*32+k] = (S_n + 2*S_k - (n==k)*S_k) / 512
    #pragma unroll
    for (int i = 0; i < 32; ++i) {
        int idx = t + 256*i;
        int bl = idx >> 10, c = idx & 1023;
        int nn = c >> 5, kk = c & 31;
        float sn = S_l[bl][nn], sk = S_l[bl][kk];
        ef[bl][c] = (sn + 2.f*sk - (nn == kk ? sk : 0.f)) * (1.f/512.f);
    }
    __syncthreads();
    int o = oT*16 + og;
    const float4* w4 = (const float4*)(W1 + o*1024);
    float acc[8] = {0.f,0.f,0.f,0.f,0.f,0.f,0.f,0.f};
    #pragma unroll
    for (int co = 0; co < 16; ++co) {
        float4 w = w4[co*16 + clane];
        #pragma unroll
        for (int bl = 0; bl < 8; ++bl) {
            float4 e = *((const float4*)&ef[bl][(co*16 + clane)*4]);
            acc[bl] += dot4(w, e);
        }
    }
    #pragma unroll
    for (int bl = 0; bl < 8; ++bl) {
        float a = acc[bl];
        a += __shfl_xor(a, 1, 16);
        a += __shfl_xor(a, 2, 16);
        a += __shfl_xor(a, 4, 16);
        a += __shfl_xor(a, 8, 16);
        acc[bl] = a;
    }
    if (clane == 0) {
        #pragma unroll
        for (int bl = 0; bl < 8; ++bl)
            Ht[(bmG*8 + bl)*512 + o] = fmaxf(acc[bl], 0.f);
    }
}

// ---------------- Kernel C: GEMM2 + sigmoid ---------------------------------
// grid (64 c-tiles of 16, 12 bm-groups); block 256 = 16 olane x 16 cg.
__global__ __launch_bounds__(256) void k3(const float* __restrict__ W2,
                                          const float* __restrict__ Ht,
                                          float* __restrict__ Et) {
    __shared__ float hl[8][512];    // 16 KB
    int t = threadIdx.x;
    int olane = t & 15, cg = t >> 4;
    int cT = blockIdx.x, bmG = blockIdx.y;
    const float4* Ht4 = (const float4*)Ht;
    #pragma unroll
    for (int i = 0; i < 4; ++i) {
        int idx = t + 256*i;              // 1024 = 8 bm x 128 f4
        int bl = idx >> 7, o4 = idx & 127;
        *((float4*)&hl[bl][o4*4]) = Ht4[(bmG*8 + bl)*128 + o4];
    }
    __syncthreads();
    int c = cT*16 + cg;
    const float4* w4 = (const float4*)(W2 + c*512);
    float acc[8] = {0.f,0.f,0.f,0.f,0.f,0.f,0.f,0.f};
    #pragma unroll
    for (int oo = 0; oo < 8; ++oo) {
        float4 w = w4[oo*16 + olane];
        #pragma unroll
        for (int bl = 0; bl < 8; ++bl) {
            float4 h = *((const float4*)&hl[bl][(oo*16 + olane)*4]);
            acc[bl] += dot4(w, h);
        }
    }
    #pragma unroll
    for (int bl = 0; bl < 8; ++bl) {
        float a = acc[bl];
        a += __shfl_xor(a, 1, 16);
        a += __shfl_xor(a, 2, 16);
        a += __shfl_xor(a, 4, 16);
        a += __shfl_xor(a, 8, 16);
        acc[bl] = a;
    }
    if (olane == 0) {
        #pragma unroll
        for (int bl = 0; bl < 8; ++bl)
            Et[(bmG*8 + bl)*1024 + c] = 1.f / (1.f + __expf(-acc[bl]));
    }
}

// ---------------- Kernel D: Gram + mask + softmax + att@x -------------------
// grid 192 = 96 bm x 2 d-halves; block 256. Gram computed redundantly per
// half (LDS/VALU-only on staged x; parallelizing across 2x CUs wins).
__global__ __launch_bounds__(256) void k4(const float* __restrict__ x,
                                          const float* __restrict__ Ssum,
                                          const float* __restrict__ Et,
                                          float* __restrict__ out) {
    int bm = blockIdx.x >> 1;
    int h  = blockIdx.x & 1;
    int t  = threadIdx.x;
    __shared__ float4 xs4[32][65];      // full 32 x 256 x tile, pad 65
    __shared__ float att_l[32][36];     // row stride 36 floats (16B aligned)
    __shared__ float S_l[32];

    const float4* x4 = (const float4*)x;
    #pragma unroll
    for (int i = 0; i < 8; ++i) {
        int idx = t + 256*i;            // 0..2047
        xs4[idx >> 6][idx & 63] = x4[bm*2048 + idx];
    }
    if (t < 32) S_l[t] = Ssum[bm*32 + t];
    __syncthreads();

    // Gram 2x2 register tile: rows (a, a+16) x (b, b+16); logits into att_l
    {
        int a = t >> 4, b = t & 15;
        float g00=0.f, g01=0.f, g10=0.f, g11=0.f;
        #pragma unroll 8
        for (int q = 0; q < 64; ++q) {
            float4 a0 = xs4[a][q],    a1 = xs4[a+16][q];
            float4 b0 = xs4[b][q],    b1 = xs4[b+16][q];
            g00 += dot4(a0,b0); g01 += dot4(a0,b1);
            g10 += dot4(a1,b0); g11 += dot4(a1,b1);
        }
        float sa0 = S_l[a]    * (1.f/256.f);
        float sa1 = S_l[a+16] * (1.f/256.f);
        float sb0 = S_l[b], sb1 = S_l[b+16];
        float e00 = Et[bm*1024 + a*32 + b];
        float e01 = Et[bm*1024 + a*32 + b+16];
        float e10 = Et[bm*1024 + (a+16)*32 + b];
        float e11 = Et[bm*1024 + (a+16)*32 + b+16];
        att_l[a][b]       = (g00 - sa0*sb0) > 0.f ? e00 : -1e12f;
        att_l[a][b+16]    = (g01 - sa0*sb1) > 0.f ? e01 : -1e12f;
        att_l[a+16][b]    = (g10 - sa1*sb0) > 0.f ? e10 : -1e12f;
        att_l[a+16][b+16] = (g11 - sa1*sb1) > 0.f ? e11 : -1e12f;
    }
    __syncthreads();

    // masked softmax per row: 8 lanes x 4 cols each
    {
        int r = t >> 3, q = t & 7;
        float4 lg = *((const float4*)&att_l[r][q*4]);
        float m = fmaxf(fmaxf(lg.x,lg.y), fmaxf(lg.z,lg.w));
        m = fmaxf(m, __shfl_xor(m,1,8));
        m = fmaxf(m, __shfl_xor(m,2,8));
        m = fmaxf(m, __shfl_xor(m,4,8));
        float4 p;
        p.x = __expf(lg.x-m); p.y = __expf(lg.y-m);
        p.z = __expf(lg.z-m); p.w = __expf(lg.w-m);
        float s = p.x+p.y+p.z+p.w;
        s += __shfl_xor(s,1,8);
        s += __shfl_xor(s,2,8);
        s += __shfl_xor(s,4,8);
        float inv = 1.f/s;
        p.x*=inv; p.y*=inv; p.z*=inv; p.w*=inv;
        *((float4*)&att_l[r][q*4]) = p;
    }
    __syncthreads();

    // out[r, d-half] = sum_k att[r,k] * x[k, d-half]; 4-row register tiles
    {
        int txl = t & 31, wy = t >> 5;   // 32 f4 cols x 8 row-groups
        int r0 = wy*4;
        float4 acc0={0,0,0,0}, acc1={0,0,0,0}, acc2={0,0,0,0}, acc3={0,0,0,0};
        #pragma unroll
        for (int kq = 0; kq < 8; ++kq) {
            float4 xa = xs4[kq*4+0][h*32 + txl];
            float4 xb = xs4[kq*4+1][h*32 + txl];
            float4 xc = xs4[kq*4+2][h*32 + txl];
            float4 xd = xs4[kq*4+3][h*32 + txl];
            float4 w0 = *((const float4*)&att_l[r0+0][kq*4]);
            float4 w1 = *((const float4*)&att_l[r0+1][kq*4]);
            float4 w2 = *((const float4*)&att_l[r0+2][kq*4]);
            float4 w3 = *((const float4*)&att_l[r0+3][kq*4]);
            fma4(acc0,w0.x,xa); fma4(acc0,w0.y,xb); fma4(acc0,w0.z,xc); fma4(acc0,w0.w,xd);
            fma4(acc1,w1.x,xa); fma4(acc1,w1.y,xb); fma4(acc1,w1.z,xc); fma4(acc1,w1.w,xd);
            fma4(acc2,w2.x,xa); fma4(acc2,w2.y,xb); fma4(acc2,w2.z,xc); fma4(acc2,w2.w,xd);
            fma4(acc3,w3.x,xa); fma4(acc3,w3.y,xb); fma4(acc3,w3.z,xc); fma4(acc3,w3.w,xd);
        }
        float4* out4 = (float4*)out;
        out4[bm*2048 + (r0+0)*64 + h*32 + txl] = acc0;
        out4[bm*2048 + (r0+1)*64 + h*32 + txl] = acc1;
        out4[bm*2048 + (r0+2)*64 + h*32 + txl] = acc2;
        out4[bm*2048 + (r0+3)*64 + h*32 + txl] = acc3;
    }
}

extern "C" void kernel_launch(void* const* d_in, const int* in_sizes, int n_in,
                              void* d_out, int out_size, void* d_ws, size_t ws_size,
                              hipStream_t stream) {
    const float* x  = (const float*)d_in[0];
    const float* W1 = (const float*)d_in[1];
    const float* W2 = (const float*)d_in[2];
    float* out = (float*)d_out;
    float* ws  = (float*)d_ws;

    float* Ssum = ws;           // 3072 floats
    float* Ht   = ws + 3072;    // 49152
    float* Et   = ws + 52224;   // 98304

    kS<<<96, 256, 0, stream>>>(x, Ssum);
    k2<<<dim3(32, 12), 256, 0, stream>>>(W1, Ssum, Ht);
    k3<<<dim3(64, 12), 256, 0, stream>>>(W2, Ht, Et);
    k4<<<192, 256, 0, stream>>>(x, Ssum, Et, out);
}